// Round 20
// baseline (92.717 us; speedup 1.0000x reference)
//
#include <hip/hip_runtime.h>
#include <hip/hip_bf16.h>
#include <stdint.h>
#include <math.h>

typedef __attribute__((ext_vector_type(8))) __bf16 bf16x8;
typedef __attribute__((ext_vector_type(4))) __bf16 bf16x4;
typedef __attribute__((ext_vector_type(4))) float f32x4;
typedef __attribute__((ext_vector_type(4), aligned(4))) float f32x4u;
typedef __attribute__((ext_vector_type(2), aligned(4))) float f32x2u;

#define B_   2
#define M_   4096
#define QH_  16
#define D_   192
#define N_   255
#define VD_  128

// K image: per (bh,jt) tile, 6144 B laid out [s(6)][g(4)][c16(16)][16B]:
//   value = K[n = jt*16 + c16][d = s*32 + g*8 + e]   (n>=255 -> 0)
// V image: per (bh,c) chunk, 8192 B laid out [vdt(8)][g(4)][c16(16)][16B]:
//   value = V[n = c*32 + g*8 + e][vd = vdt*16 + c16] (n>=255 -> 0)
// Every 16B lane-load is part of a 1024B contiguous wave access (coalesced).

__global__ __launch_bounds__(256) void prep_k(const float* __restrict__ k,
                                              __bf16* __restrict__ kimg) {
    const int chunk = blockIdx.x * 256 + threadIdx.x;   // 196608 chunks
    const int wc   = chunk % 384;
    const int tile = chunk / 384;          // bh*16 + jt
    const int c16  = wc & 15;
    const int gq   = (wc >> 4) & 3;
    const int s    = wc >> 6;              // 0..5
    const int jt   = tile & 15;
    const int bh   = tile >> 4;
    const int b    = bh >> 4, h = bh & 15;
    const int n    = jt * 16 + c16;
    bf16x8 out;
    if (n < N_) {
        const float* src = k + ((size_t)((b * N_ + n) * QH_ + h)) * D_ + s * 32 + gq * 8;
        f32x4 s0 = *(const f32x4*)src;
        f32x4 s1 = *(const f32x4*)(src + 4);
        out[0]=(__bf16)s0[0]; out[1]=(__bf16)s0[1]; out[2]=(__bf16)s0[2]; out[3]=(__bf16)s0[3];
        out[4]=(__bf16)s1[0]; out[5]=(__bf16)s1[1]; out[6]=(__bf16)s1[2]; out[7]=(__bf16)s1[3];
    } else {
        #pragma unroll
        for (int e = 0; e < 8; ++e) out[e] = (__bf16)0.f;
    }
    *(bf16x8*)(kimg + (size_t)chunk * 8) = out;
}

__global__ __launch_bounds__(256) void prep_v(const float* __restrict__ v,
                                              __bf16* __restrict__ vimg) {
    const int chunk = blockIdx.x * 256 + threadIdx.x;   // 131072 chunks
    const int wc  = chunk & 511;
    const int img = chunk >> 9;            // bh*8 + c
    const int c16 = wc & 15;
    const int gq  = (wc >> 4) & 3;
    const int vdt = wc >> 6;               // 0..7
    const int c   = img & 7;
    const int bh  = img >> 3;
    const int b   = bh >> 4, h = bh & 15;
    const int vd  = vdt * 16 + c16;
    const int n0  = c * 32 + gq * 8;
    bf16x8 out;
    #pragma unroll
    for (int t = 0; t < 8; ++t) {
        const int n = n0 + t;
        float val = (n < N_) ? v[((size_t)((b * N_ + n) * QH_ + h)) * VD_ + vd] : 0.f;
        out[t] = (__bf16)val;
    }
    *(bf16x8*)(vimg + (size_t)chunk * 8) = out;
}

// ---- fused kernel (R19 body). R20 delta: NT o-stores (kill ~55 MB of
// write-allocate HBM fetch; o rows are fully-written 512B -> NT is safe).
__global__ __launch_bounds__(64) void cattn_kernel(
    const float* __restrict__ q, const __bf16* __restrict__ kimg,
    const __bf16* __restrict__ vimg, float* __restrict__ o_out,
    float* __restrict__ p_out)
{
    const float scale = 0.07216878364870322f; // 192^-0.5
    const int bid  = blockIdx.x;
    const int xcd  = bid & 7;             // consecutive bids round-robin XCDs
    const int loc  = bid >> 3;
    const int bh   = xcd * 4 + (loc & 3); // 4 heads per XCD -> 640 KB hot set
    const int iw16 = 255 - (loc >> 2);    // heavy q-tiles dispatched first
    const int h    = bh & 15;
    const int b    = bh >> 4;

    const int lane = threadIdx.x;   // 0..63
    const int g    = lane >> 4;     // 0..3
    const int c16  = lane & 15;
    const int iw   = iw16 << 4;
    const int i    = iw + c16;          // this lane's q row
    const bool dead = (i < 31);         // fully-masked row -> uniform 1/255

    // ---- Q fragment (B-operand): bq[s][e] = Q[i][s*32 + g*8 + e]
    bf16x8 bq[6];
    {
        const float* qrow = q + ((size_t)((b * M_ + i) * QH_ + h)) * D_;
        #pragma unroll
        for (int s = 0; s < 6; ++s) {
            f32x4 q0 = __builtin_nontemporal_load((const f32x4*)(qrow + s * 32 + g * 8));
            f32x4 q1 = __builtin_nontemporal_load((const f32x4*)(qrow + s * 32 + g * 8 + 4));
            bf16x8 a;
            a[0]=(__bf16)q0[0]; a[1]=(__bf16)q0[1]; a[2]=(__bf16)q0[2]; a[3]=(__bf16)q0[3];
            a[4]=(__bf16)q1[0]; a[5]=(__bf16)q1[1]; a[6]=(__bf16)q1[2]; a[7]=(__bf16)q1[3];
            bq[s] = a;
        }
    }

    int jt_any = (iw >= 16) ? ((iw - 16) >> 8) : -1;
    if (jt_any > 15) jt_any = 15;

    f32x4 sacc[16];
    #pragma unroll
    for (int jt = 0; jt < 16; ++jt)
        sacc[jt] = (f32x4){-INFINITY, -INFINITY, -INFINITY, -INFINITY};

    const __bf16* kbh = kimg + (size_t)(bh * 16) * 3072 + g * 128 + c16 * 8;

    // double-buffered K fragments (static names -> registers)
    bf16x8 kfA[6], kfB[6];
    if (jt_any >= 0) {
        #pragma unroll
        for (int s = 0; s < 6; ++s) kfA[s] = *(const bf16x8*)(kbh + s * 512);
    }

#define QK_STEP(JT, KCUR, KNXT)                                                \
    if ((JT) <= jt_any) {                                                      \
        if ((JT) + 1 <= jt_any) {                                              \
            const __bf16* kr = kbh + (size_t)((JT) + 1) * 3072;                \
            _Pragma("unroll")                                                  \
            for (int s = 0; s < 6; ++s) KNXT[s] = *(const bf16x8*)(kr + s*512);\
        }                                                                      \
        f32x4 acc = {0.f, 0.f, 0.f, 0.f};                                      \
        _Pragma("unroll")                                                      \
        for (int s = 0; s < 6; ++s)                                            \
            acc = __builtin_amdgcn_mfma_f32_16x16x32_bf16(KCUR[s], bq[s], acc, 0, 0, 0); \
        _Pragma("unroll")                                                      \
        for (int r = 0; r < 4; ++r) {                                          \
            const int n = (JT) * 16 + g * 4 + r;                               \
            const bool live = (n < N_) && (i >= 16 * n + 31);                  \
            acc[r] = live ? acc[r] * scale : ((n < N_) ? -1e30f : -INFINITY);  \
        }                                                                      \
        sacc[(JT)] = acc;                                                      \
    }

    QK_STEP(0,  kfA, kfB)  QK_STEP(1,  kfB, kfA)
    QK_STEP(2,  kfA, kfB)  QK_STEP(3,  kfB, kfA)
    QK_STEP(4,  kfA, kfB)  QK_STEP(5,  kfB, kfA)
    QK_STEP(6,  kfA, kfB)  QK_STEP(7,  kfB, kfA)
    QK_STEP(8,  kfA, kfB)  QK_STEP(9,  kfB, kfA)
    QK_STEP(10, kfA, kfB)  QK_STEP(11, kfB, kfA)
    QK_STEP(12, kfA, kfB)  QK_STEP(13, kfB, kfA)
    QK_STEP(14, kfA, kfB)  QK_STEP(15, kfB, kfA)
#undef QK_STEP

    // ---- hoisted V chunk-0 prefetch: latency hides under softmax VALU below
    const int c_lim = (jt_any < 0) ? 0 : ((jt_any + 2) >> 1);
    const __bf16* vth = vimg + (size_t)(bh * 8) * 4096 + g * 128 + c16 * 8;
    bf16x8 vbA[8], vbB[8];
    if (0 < c_lim) {
        #pragma unroll
        for (int t = 0; t < 8; ++t) vbA[t] = *(const bf16x8*)(vth + t * 512);
    }

    // ---- softmax over this lane's row: 4 independent per-r partial chains
    float m0 = -INFINITY, m1 = -INFINITY, m2 = -INFINITY, m3 = -INFINITY;
    #pragma unroll
    for (int jt = 0; jt < 16; ++jt) {
        m0 = fmaxf(m0, sacc[jt][0]);
        m1 = fmaxf(m1, sacc[jt][1]);
        m2 = fmaxf(m2, sacc[jt][2]);
        m3 = fmaxf(m3, sacc[jt][3]);
    }
    float m = fmaxf(fmaxf(m0, m1), fmaxf(m2, m3));
    m = fmaxf(m, __shfl_xor(m, 16));
    m = fmaxf(m, __shfl_xor(m, 32));
    float s0 = 0.f, s1 = 0.f, s2 = 0.f, s3 = 0.f;
    #pragma unroll
    for (int jt = 0; jt < 16; ++jt) {
        float e0 = __expf(sacc[jt][0] - m);
        float e1 = __expf(sacc[jt][1] - m);
        float e2 = __expf(sacc[jt][2] - m);
        float e3 = __expf(sacc[jt][3] - m);
        sacc[jt][0] = e0; sacc[jt][1] = e1;
        sacc[jt][2] = e2; sacc[jt][3] = e3;
        s0 += e0; s1 += e1; s2 += e2; s3 += e3;
    }
    float sum = (s0 + s1) + (s2 + s3);
    sum += __shfl_xor(sum, 16);
    sum += __shfl_xor(sum, 32);
    const float inv_l = 1.0f / sum;
    const float u255  = 0.00392156862745098f;  // 1/255 for dead rows

    // ---- normalize, store p (vector, cached), pack bf16x4 -> u64 (sacc dies)
    unsigned long long pnp[16];
    float* prow = p_out + (size_t)(bh * M_ + i) * N_ + g * 4;
    #pragma unroll
    for (int jt = 0; jt < 16; ++jt) {
        f32x4 px;
        #pragma unroll
        for (int r = 0; r < 4; ++r)
            px[r] = dead ? u255 : sacc[jt][r] * inv_l;
        if (jt == 15 && g == 3) {
            f32x2u p2; p2[0] = px[0]; p2[1] = px[1];     // cols 252..254 only
            *(f32x2u*)(prow + 15 * 16) = p2;
            prow[15 * 16 + 2] = px[2];
        } else {
            *(f32x4u*)(prow + jt * 16) = *(f32x4u*)&px;
        }
        union { bf16x4 v; unsigned long long u; } pk;
        #pragma unroll
        for (int r = 0; r < 4; ++r) pk.v[r] = (__bf16)px[r];
        pnp[jt] = pk.u;
    }

    // ---- PV phase: O^T = V^T P^T ; lane (g,c16) holds O[i][vd = vdt*16+g*4+r]
    f32x4 oacc[8];
    #pragma unroll
    for (int t = 0; t < 8; ++t) oacc[t] = (f32x4){0.f, 0.f, 0.f, 0.f};

    const int src0 = ((g & 1) << 5) + c16;   // lane (g_s=(g&1)*2, c16)
    const int src1 = src0 + 16;              // lane (g_s=(g&1)*2+1, c16)
    const bool selhi = (g >= 2);

#define PV_STEP(C, VBc, VBn)                                                   \
    if ((C) < c_lim) {                                                         \
        if ((C) + 1 < c_lim) {                                                 \
            const __bf16* vc = vth + (size_t)((C) + 1) * 4096;                 \
            _Pragma("unroll")                                                  \
            for (int t = 0; t < 8; ++t) VBn[t] = *(const bf16x8*)(vc + t*512); \
        }                                                                      \
        unsigned long long lo0 = __shfl(pnp[2 * (C)],     src0);               \
        unsigned long long lo1 = __shfl(pnp[2 * (C) + 1], src0);               \
        unsigned long long hi0 = __shfl(pnp[2 * (C)],     src1);               \
        unsigned long long hi1 = __shfl(pnp[2 * (C) + 1], src1);               \
        union { struct { unsigned long long x, y; } u; bf16x8 v; } pa8;        \
        pa8.u.x = selhi ? lo1 : lo0;                                           \
        pa8.u.y = selhi ? hi1 : hi0;                                           \
        const bf16x8 pa = pa8.v;                                               \
        _Pragma("unroll")                                                      \
        for (int vdt = 0; vdt < 8; ++vdt)                                      \
            oacc[vdt] = __builtin_amdgcn_mfma_f32_16x16x32_bf16(VBc[vdt], pa, oacc[vdt], 0, 0, 0); \
    }

    PV_STEP(0, vbA, vbB)
    PV_STEP(1, vbB, vbA)
    PV_STEP(2, vbA, vbB)
    PV_STEP(3, vbB, vbA)
    PV_STEP(4, vbA, vbB)
    PV_STEP(5, vbB, vbA)
    PV_STEP(6, vbA, vbB)
    PV_STEP(7, vbB, vbA)
#undef PV_STEP

    // ---- write O: NT stores (16 full 64B sectors per instr -> no write-
    // allocate fetch, no L2 pollution of the hot K/V set); rows < 31 zeroed
    float* orow = o_out + ((size_t)(b * M_ + i) * QH_ + h) * VD_ + g * 4;
    #pragma unroll
    for (int vdt = 0; vdt < 8; ++vdt) {
        f32x4 ov;
        #pragma unroll
        for (int r = 0; r < 4; ++r) ov[r] = dead ? 0.f : oacc[vdt][r];
        __builtin_nontemporal_store(ov, (f32x4*)(orow + vdt * 16));
    }
}

extern "C" void kernel_launch(void* const* d_in, const int* in_sizes, int n_in,
                              void* d_out, int out_size, void* d_ws, size_t ws_size,
                              hipStream_t stream) {
    (void)in_sizes; (void)n_in; (void)ws_size; (void)out_size;
    const float* q = (const float*)d_in[0];
    const float* k = (const float*)d_in[1];
    const float* v = (const float*)d_in[2];
    float* o_out = (float*)d_out;
    float* p_out = o_out + (size_t)B_ * M_ * QH_ * VD_;   // tuple: (o, p) flat

    __bf16* kimg = (__bf16*)d_ws;                          // 32*16*3072*2B = 3.0 MB
    __bf16* vimg = kimg + (size_t)32 * 16 * 3072;          // 32*8*4096*2B  = 2.0 MB

    prep_k<<<dim3(768), dim3(256), 0, stream>>>(k, kimg);
    prep_v<<<dim3(512), dim3(256), 0, stream>>>(v, vimg);

    dim3 grid(B_ * QH_ * 256);   // 8192 one-wave blocks; bid&7 = XCD head-group
    dim3 block(64);
    cattn_kernel<<<grid, block, 0, stream>>>(q, kimg, vimg, o_out, p_out);
}

// Round 21
// 90.064 us; speedup vs baseline: 1.0295x; 1.0295x over previous
//
#include <hip/hip_runtime.h>
#include <hip/hip_bf16.h>
#include <stdint.h>
#include <math.h>

typedef __attribute__((ext_vector_type(8))) __bf16 bf16x8;
typedef __attribute__((ext_vector_type(4))) __bf16 bf16x4;
typedef __attribute__((ext_vector_type(4))) float f32x4;
typedef __attribute__((ext_vector_type(4), aligned(4))) float f32x4u;
typedef __attribute__((ext_vector_type(2), aligned(4))) float f32x2u;

#define B_   2
#define M_   4096
#define QH_  16
#define D_   192
#define N_   255
#define VD_  128

// K image: per (bh,jt) tile, 6144 B laid out [s(6)][g(4)][c16(16)][16B]:
//   value = K[n = jt*16 + c16][d = s*32 + g*8 + e]   (n>=255 -> 0)
// V image: per (bh,c) chunk, 8192 B laid out [vdt(8)][g(4)][c16(16)][16B]:
//   value = V[n = c*32 + g*8 + e][vd = vdt*16 + c16] (n>=255 -> 0)
// Every 16B lane-load is part of a 1024B contiguous wave access (coalesced).

__global__ __launch_bounds__(256) void prep_k(const float* __restrict__ k,
                                              __bf16* __restrict__ kimg) {
    const int chunk = blockIdx.x * 256 + threadIdx.x;   // 196608 chunks
    const int wc   = chunk % 384;
    const int tile = chunk / 384;          // bh*16 + jt
    const int c16  = wc & 15;
    const int gq   = (wc >> 4) & 3;
    const int s    = wc >> 6;              // 0..5
    const int jt   = tile & 15;
    const int bh   = tile >> 4;
    const int b    = bh >> 4, h = bh & 15;
    const int n    = jt * 16 + c16;
    bf16x8 out;
    if (n < N_) {
        const float* src = k + ((size_t)((b * N_ + n) * QH_ + h)) * D_ + s * 32 + gq * 8;
        f32x4 s0 = *(const f32x4*)src;
        f32x4 s1 = *(const f32x4*)(src + 4);
        out[0]=(__bf16)s0[0]; out[1]=(__bf16)s0[1]; out[2]=(__bf16)s0[2]; out[3]=(__bf16)s0[3];
        out[4]=(__bf16)s1[0]; out[5]=(__bf16)s1[1]; out[6]=(__bf16)s1[2]; out[7]=(__bf16)s1[3];
    } else {
        #pragma unroll
        for (int e = 0; e < 8; ++e) out[e] = (__bf16)0.f;
    }
    *(bf16x8*)(kimg + (size_t)chunk * 8) = out;
}

__global__ __launch_bounds__(256) void prep_v(const float* __restrict__ v,
                                              __bf16* __restrict__ vimg) {
    const int chunk = blockIdx.x * 256 + threadIdx.x;   // 131072 chunks
    const int wc  = chunk & 511;
    const int img = chunk >> 9;            // bh*8 + c
    const int c16 = wc & 15;
    const int gq  = (wc >> 4) & 3;
    const int vdt = wc >> 6;               // 0..7
    const int c   = img & 7;
    const int bh  = img >> 3;
    const int b   = bh >> 4, h = bh & 15;
    const int vd  = vdt * 16 + c16;
    const int n0  = c * 32 + gq * 8;
    bf16x8 out;
    #pragma unroll
    for (int t = 0; t < 8; ++t) {
        const int n = n0 + t;
        float val = (n < N_) ? v[((size_t)((b * N_ + n) * QH_ + h)) * VD_ + vd] : 0.f;
        out[t] = (__bf16)val;
    }
    *(bf16x8*)(vimg + (size_t)chunk * 8) = out;
}

// ---- fused kernel (R19 body + T5 setprio around MFMA clusters).
// 1-wave independent blocks at staggered phases = m191's setprio-wins regime.
__global__ __launch_bounds__(64) void cattn_kernel(
    const float* __restrict__ q, const __bf16* __restrict__ kimg,
    const __bf16* __restrict__ vimg, float* __restrict__ o_out,
    float* __restrict__ p_out)
{
    const float scale = 0.07216878364870322f; // 192^-0.5
    const int bid  = blockIdx.x;
    const int xcd  = bid & 7;             // consecutive bids round-robin XCDs
    const int loc  = bid >> 3;
    const int bh   = xcd * 4 + (loc & 3); // 4 heads per XCD -> 640 KB hot set
    const int iw16 = 255 - (loc >> 2);    // heavy q-tiles dispatched first
    const int h    = bh & 15;
    const int b    = bh >> 4;

    const int lane = threadIdx.x;   // 0..63
    const int g    = lane >> 4;     // 0..3
    const int c16  = lane & 15;
    const int iw   = iw16 << 4;
    const int i    = iw + c16;          // this lane's q row
    const bool dead = (i < 31);         // fully-masked row -> uniform 1/255

    // ---- Q fragment (B-operand): bq[s][e] = Q[i][s*32 + g*8 + e]
    bf16x8 bq[6];
    {
        const float* qrow = q + ((size_t)((b * M_ + i) * QH_ + h)) * D_;
        #pragma unroll
        for (int s = 0; s < 6; ++s) {
            f32x4 q0 = __builtin_nontemporal_load((const f32x4*)(qrow + s * 32 + g * 8));
            f32x4 q1 = __builtin_nontemporal_load((const f32x4*)(qrow + s * 32 + g * 8 + 4));
            bf16x8 a;
            a[0]=(__bf16)q0[0]; a[1]=(__bf16)q0[1]; a[2]=(__bf16)q0[2]; a[3]=(__bf16)q0[3];
            a[4]=(__bf16)q1[0]; a[5]=(__bf16)q1[1]; a[6]=(__bf16)q1[2]; a[7]=(__bf16)q1[3];
            bq[s] = a;
        }
    }

    int jt_any = (iw >= 16) ? ((iw - 16) >> 8) : -1;
    if (jt_any > 15) jt_any = 15;

    f32x4 sacc[16];
    #pragma unroll
    for (int jt = 0; jt < 16; ++jt)
        sacc[jt] = (f32x4){-INFINITY, -INFINITY, -INFINITY, -INFINITY};

    const __bf16* kbh = kimg + (size_t)(bh * 16) * 3072 + g * 128 + c16 * 8;

    // double-buffered K fragments (static names -> registers)
    bf16x8 kfA[6], kfB[6];
    if (jt_any >= 0) {
        #pragma unroll
        for (int s = 0; s < 6; ++s) kfA[s] = *(const bf16x8*)(kbh + s * 512);
    }

#define QK_STEP(JT, KCUR, KNXT)                                                \
    if ((JT) <= jt_any) {                                                      \
        if ((JT) + 1 <= jt_any) {                                              \
            const __bf16* kr = kbh + (size_t)((JT) + 1) * 3072;                \
            _Pragma("unroll")                                                  \
            for (int s = 0; s < 6; ++s) KNXT[s] = *(const bf16x8*)(kr + s*512);\
        }                                                                      \
        f32x4 acc = {0.f, 0.f, 0.f, 0.f};                                      \
        __builtin_amdgcn_s_setprio(1);                                         \
        _Pragma("unroll")                                                      \
        for (int s = 0; s < 6; ++s)                                            \
            acc = __builtin_amdgcn_mfma_f32_16x16x32_bf16(KCUR[s], bq[s], acc, 0, 0, 0); \
        __builtin_amdgcn_s_setprio(0);                                         \
        _Pragma("unroll")                                                      \
        for (int r = 0; r < 4; ++r) {                                          \
            const int n = (JT) * 16 + g * 4 + r;                               \
            const bool live = (n < N_) && (i >= 16 * n + 31);                  \
            acc[r] = live ? acc[r] * scale : ((n < N_) ? -1e30f : -INFINITY);  \
        }                                                                      \
        sacc[(JT)] = acc;                                                      \
    }

    QK_STEP(0,  kfA, kfB)  QK_STEP(1,  kfB, kfA)
    QK_STEP(2,  kfA, kfB)  QK_STEP(3,  kfB, kfA)
    QK_STEP(4,  kfA, kfB)  QK_STEP(5,  kfB, kfA)
    QK_STEP(6,  kfA, kfB)  QK_STEP(7,  kfB, kfA)
    QK_STEP(8,  kfA, kfB)  QK_STEP(9,  kfB, kfA)
    QK_STEP(10, kfA, kfB)  QK_STEP(11, kfB, kfA)
    QK_STEP(12, kfA, kfB)  QK_STEP(13, kfB, kfA)
    QK_STEP(14, kfA, kfB)  QK_STEP(15, kfB, kfA)
#undef QK_STEP

    // ---- hoisted V chunk-0 prefetch: latency hides under softmax VALU below
    const int c_lim = (jt_any < 0) ? 0 : ((jt_any + 2) >> 1);
    const __bf16* vth = vimg + (size_t)(bh * 8) * 4096 + g * 128 + c16 * 8;
    bf16x8 vbA[8], vbB[8];
    if (0 < c_lim) {
        #pragma unroll
        for (int t = 0; t < 8; ++t) vbA[t] = *(const bf16x8*)(vth + t * 512);
    }

    // ---- softmax over this lane's row: 4 independent per-r partial chains
    float m0 = -INFINITY, m1 = -INFINITY, m2 = -INFINITY, m3 = -INFINITY;
    #pragma unroll
    for (int jt = 0; jt < 16; ++jt) {
        m0 = fmaxf(m0, sacc[jt][0]);
        m1 = fmaxf(m1, sacc[jt][1]);
        m2 = fmaxf(m2, sacc[jt][2]);
        m3 = fmaxf(m3, sacc[jt][3]);
    }
    float m = fmaxf(fmaxf(m0, m1), fmaxf(m2, m3));
    m = fmaxf(m, __shfl_xor(m, 16));
    m = fmaxf(m, __shfl_xor(m, 32));
    float s0 = 0.f, s1 = 0.f, s2 = 0.f, s3 = 0.f;
    #pragma unroll
    for (int jt = 0; jt < 16; ++jt) {
        float e0 = __expf(sacc[jt][0] - m);
        float e1 = __expf(sacc[jt][1] - m);
        float e2 = __expf(sacc[jt][2] - m);
        float e3 = __expf(sacc[jt][3] - m);
        sacc[jt][0] = e0; sacc[jt][1] = e1;
        sacc[jt][2] = e2; sacc[jt][3] = e3;
        s0 += e0; s1 += e1; s2 += e2; s3 += e3;
    }
    float sum = (s0 + s1) + (s2 + s3);
    sum += __shfl_xor(sum, 16);
    sum += __shfl_xor(sum, 32);
    const float inv_l = 1.0f / sum;
    const float u255  = 0.00392156862745098f;  // 1/255 for dead rows

    // ---- normalize, store p (vector, cached), pack bf16x4 -> u64 (sacc dies)
    unsigned long long pnp[16];
    float* prow = p_out + (size_t)(bh * M_ + i) * N_ + g * 4;
    #pragma unroll
    for (int jt = 0; jt < 16; ++jt) {
        f32x4 px;
        #pragma unroll
        for (int r = 0; r < 4; ++r)
            px[r] = dead ? u255 : sacc[jt][r] * inv_l;
        if (jt == 15 && g == 3) {
            f32x2u p2; p2[0] = px[0]; p2[1] = px[1];     // cols 252..254 only
            *(f32x2u*)(prow + 15 * 16) = p2;
            prow[15 * 16 + 2] = px[2];
        } else {
            *(f32x4u*)(prow + jt * 16) = *(f32x4u*)&px;
        }
        union { bf16x4 v; unsigned long long u; } pk;
        #pragma unroll
        for (int r = 0; r < 4; ++r) pk.v[r] = (__bf16)px[r];
        pnp[jt] = pk.u;
    }

    // ---- PV phase: O^T = V^T P^T ; lane (g,c16) holds O[i][vd = vdt*16+g*4+r]
    f32x4 oacc[8];
    #pragma unroll
    for (int t = 0; t < 8; ++t) oacc[t] = (f32x4){0.f, 0.f, 0.f, 0.f};

    const int src0 = ((g & 1) << 5) + c16;   // lane (g_s=(g&1)*2, c16)
    const int src1 = src0 + 16;              // lane (g_s=(g&1)*2+1, c16)
    const bool selhi = (g >= 2);

#define PV_STEP(C, VBc, VBn)                                                   \
    if ((C) < c_lim) {                                                         \
        if ((C) + 1 < c_lim) {                                                 \
            const __bf16* vc = vth + (size_t)((C) + 1) * 4096;                 \
            _Pragma("unroll")                                                  \
            for (int t = 0; t < 8; ++t) VBn[t] = *(const bf16x8*)(vc + t*512); \
        }                                                                      \
        unsigned long long lo0 = __shfl(pnp[2 * (C)],     src0);               \
        unsigned long long lo1 = __shfl(pnp[2 * (C) + 1], src0);               \
        unsigned long long hi0 = __shfl(pnp[2 * (C)],     src1);               \
        unsigned long long hi1 = __shfl(pnp[2 * (C) + 1], src1);               \
        union { struct { unsigned long long x, y; } u; bf16x8 v; } pa8;        \
        pa8.u.x = selhi ? lo1 : lo0;                                           \
        pa8.u.y = selhi ? hi1 : hi0;                                           \
        const bf16x8 pa = pa8.v;                                               \
        __builtin_amdgcn_s_setprio(1);                                         \
        _Pragma("unroll")                                                      \
        for (int vdt = 0; vdt < 8; ++vdt)                                      \
            oacc[vdt] = __builtin_amdgcn_mfma_f32_16x16x32_bf16(VBc[vdt], pa, oacc[vdt], 0, 0, 0); \
        __builtin_amdgcn_s_setprio(0);                                         \
    }

    PV_STEP(0, vbA, vbB)
    PV_STEP(1, vbB, vbA)
    PV_STEP(2, vbA, vbB)
    PV_STEP(3, vbB, vbA)
    PV_STEP(4, vbA, vbB)
    PV_STEP(5, vbB, vbA)
    PV_STEP(6, vbA, vbB)
    PV_STEP(7, vbB, vbA)
#undef PV_STEP

    // ---- write O (plain cached dwordx4; rows < 31 forced to zero)
    float* orow = o_out + ((size_t)(b * M_ + i) * QH_ + h) * VD_ + g * 4;
    #pragma unroll
    for (int vdt = 0; vdt < 8; ++vdt) {
        f32x4 ov;
        #pragma unroll
        for (int r = 0; r < 4; ++r) ov[r] = dead ? 0.f : oacc[vdt][r];
        *(f32x4*)(orow + vdt * 16) = ov;
    }
}

extern "C" void kernel_launch(void* const* d_in, const int* in_sizes, int n_in,
                              void* d_out, int out_size, void* d_ws, size_t ws_size,
                              hipStream_t stream) {
    (void)in_sizes; (void)n_in; (void)ws_size; (void)out_size;
    const float* q = (const float*)d_in[0];
    const float* k = (const float*)d_in[1];
    const float* v = (const float*)d_in[2];
    float* o_out = (float*)d_out;
    float* p_out = o_out + (size_t)B_ * M_ * QH_ * VD_;   // tuple: (o, p) flat

    __bf16* kimg = (__bf16*)d_ws;                          // 32*16*3072*2B = 3.0 MB
    __bf16* vimg = kimg + (size_t)32 * 16 * 3072;          // 32*8*4096*2B  = 2.0 MB

    prep_k<<<dim3(768), dim3(256), 0, stream>>>(k, kimg);
    prep_v<<<dim3(512), dim3(256), 0, stream>>>(v, vimg);

    dim3 grid(B_ * QH_ * 256);   // 8192 one-wave blocks; bid&7 = XCD head-group
    dim3 block(64);
    cattn_kernel<<<grid, block, 0, stream>>>(q, kimg, vimg, o_out, p_out);
}

// Round 23
// 87.553 us; speedup vs baseline: 1.0590x; 1.0287x over previous
//
#include <hip/hip_runtime.h>
#include <hip/hip_bf16.h>
#include <stdint.h>
#include <math.h>

typedef __attribute__((ext_vector_type(8))) __bf16 bf16x8;
typedef __attribute__((ext_vector_type(4))) __bf16 bf16x4;
typedef __attribute__((ext_vector_type(4))) float f32x4;
typedef __attribute__((ext_vector_type(4), aligned(4))) float f32x4u;
typedef __attribute__((ext_vector_type(2), aligned(4))) float f32x2u;

#define B_   2
#define M_   4096
#define QH_  16
#define D_   192
#define N_   255
#define VD_  128

// K image: per (bh,jt) tile, 6144 B laid out [s(6)][g(4)][c16(16)][16B]:
//   value = K[n = jt*16 + c16][d = s*32 + g*8 + e]   (n>=255 -> 0)
// V image: per (bh,c) chunk, 8192 B laid out [vdt(8)][g(4)][c16(16)][16B]:
//   value = V[n = c*32 + g*8 + e][vd = vdt*16 + c16] (n>=255 -> 0)
// Every 16B lane-load is part of a 1024B contiguous wave access (coalesced).

// merged prep: blocks [0,768) build kimg, blocks [768,1280) build vimg
__global__ __launch_bounds__(256) void prep_kv(const float* __restrict__ k,
                                               const float* __restrict__ v,
                                               __bf16* __restrict__ kimg,
                                               __bf16* __restrict__ vimg) {
    if (blockIdx.x < 768) {
        const int chunk = blockIdx.x * 256 + threadIdx.x;   // 196608 chunks
        const int wc   = chunk % 384;
        const int tile = chunk / 384;          // bh*16 + jt
        const int c16  = wc & 15;
        const int gq   = (wc >> 4) & 3;
        const int s    = wc >> 6;              // 0..5
        const int jt   = tile & 15;
        const int bh   = tile >> 4;
        const int b    = bh >> 4, h = bh & 15;
        const int n    = jt * 16 + c16;
        bf16x8 out;
        if (n < N_) {
            const float* src = k + ((size_t)((b * N_ + n) * QH_ + h)) * D_ + s * 32 + gq * 8;
            f32x4 s0 = *(const f32x4*)src;
            f32x4 s1 = *(const f32x4*)(src + 4);
            out[0]=(__bf16)s0[0]; out[1]=(__bf16)s0[1]; out[2]=(__bf16)s0[2]; out[3]=(__bf16)s0[3];
            out[4]=(__bf16)s1[0]; out[5]=(__bf16)s1[1]; out[6]=(__bf16)s1[2]; out[7]=(__bf16)s1[3];
        } else {
            #pragma unroll
            for (int e = 0; e < 8; ++e) out[e] = (__bf16)0.f;
        }
        *(bf16x8*)(kimg + (size_t)chunk * 8) = out;
    } else {
        const int chunk = (blockIdx.x - 768) * 256 + threadIdx.x;   // 131072 chunks
        const int wc  = chunk & 511;
        const int img = chunk >> 9;            // bh*8 + c
        const int c16 = wc & 15;
        const int gq  = (wc >> 4) & 3;
        const int vdt = wc >> 6;               // 0..7
        const int c   = img & 7;
        const int bh  = img >> 3;
        const int b   = bh >> 4, h = bh & 15;
        const int vd  = vdt * 16 + c16;
        const int n0  = c * 32 + gq * 8;
        bf16x8 out;
        #pragma unroll
        for (int t = 0; t < 8; ++t) {
            const int n = n0 + t;
            float val = (n < N_) ? v[((size_t)((b * N_ + n) * QH_ + h)) * VD_ + vd] : 0.f;
            out[t] = (__bf16)val;
        }
        *(bf16x8*)(vimg + (size_t)chunk * 8) = out;
    }
}

// ---- fused kernel (R21/R19 body: XCD-confined heads, reg-dbuf prefetch,
// setprio on MFMA clusters, plain cached stores). Best verified: 90.06 us.
__global__ __launch_bounds__(64) void cattn_kernel(
    const float* __restrict__ q, const __bf16* __restrict__ kimg,
    const __bf16* __restrict__ vimg, float* __restrict__ o_out,
    float* __restrict__ p_out)
{
    const float scale = 0.07216878364870322f; // 192^-0.5
    const int bid  = blockIdx.x;
    const int xcd  = bid & 7;             // consecutive bids round-robin XCDs
    const int loc  = bid >> 3;
    const int bh   = xcd * 4 + (loc & 3); // 4 heads per XCD -> 640 KB hot set
    const int iw16 = 255 - (loc >> 2);    // heavy q-tiles dispatched first
    const int h    = bh & 15;
    const int b    = bh >> 4;

    const int lane = threadIdx.x;   // 0..63
    const int g    = lane >> 4;     // 0..3
    const int c16  = lane & 15;
    const int iw   = iw16 << 4;
    const int i    = iw + c16;          // this lane's q row
    const bool dead = (i < 31);         // fully-masked row -> uniform 1/255

    // ---- Q fragment (B-operand): bq[s][e] = Q[i][s*32 + g*8 + e]
    bf16x8 bq[6];
    {
        const float* qrow = q + ((size_t)((b * M_ + i) * QH_ + h)) * D_;
        #pragma unroll
        for (int s = 0; s < 6; ++s) {
            f32x4 q0 = __builtin_nontemporal_load((const f32x4*)(qrow + s * 32 + g * 8));
            f32x4 q1 = __builtin_nontemporal_load((const f32x4*)(qrow + s * 32 + g * 8 + 4));
            bf16x8 a;
            a[0]=(__bf16)q0[0]; a[1]=(__bf16)q0[1]; a[2]=(__bf16)q0[2]; a[3]=(__bf16)q0[3];
            a[4]=(__bf16)q1[0]; a[5]=(__bf16)q1[1]; a[6]=(__bf16)q1[2]; a[7]=(__bf16)q1[3];
            bq[s] = a;
        }
    }

    int jt_any = (iw >= 16) ? ((iw - 16) >> 8) : -1;
    if (jt_any > 15) jt_any = 15;

    f32x4 sacc[16];
    #pragma unroll
    for (int jt = 0; jt < 16; ++jt)
        sacc[jt] = (f32x4){-INFINITY, -INFINITY, -INFINITY, -INFINITY};

    const __bf16* kbh = kimg + (size_t)(bh * 16) * 3072 + g * 128 + c16 * 8;

    // double-buffered K fragments (static names -> registers)
    bf16x8 kfA[6], kfB[6];
    if (jt_any >= 0) {
        #pragma unroll
        for (int s = 0; s < 6; ++s) kfA[s] = *(const bf16x8*)(kbh + s * 512);
    }

#define QK_STEP(JT, KCUR, KNXT)                                                \
    if ((JT) <= jt_any) {                                                      \
        if ((JT) + 1 <= jt_any) {                                              \
            const __bf16* kr = kbh + (size_t)((JT) + 1) * 3072;                \
            _Pragma("unroll")                                                  \
            for (int s = 0; s < 6; ++s) KNXT[s] = *(const bf16x8*)(kr + s*512);\
        }                                                                      \
        f32x4 acc = {0.f, 0.f, 0.f, 0.f};                                      \
        __builtin_amdgcn_s_setprio(1);                                         \
        _Pragma("unroll")                                                      \
        for (int s = 0; s < 6; ++s)                                            \
            acc = __builtin_amdgcn_mfma_f32_16x16x32_bf16(KCUR[s], bq[s], acc, 0, 0, 0); \
        __builtin_amdgcn_s_setprio(0);                                         \
        _Pragma("unroll")                                                      \
        for (int r = 0; r < 4; ++r) {                                          \
            const int n = (JT) * 16 + g * 4 + r;                               \
            const bool live = (n < N_) && (i >= 16 * n + 31);                  \
            acc[r] = live ? acc[r] * scale : ((n < N_) ? -1e30f : -INFINITY);  \
        }                                                                      \
        sacc[(JT)] = acc;                                                      \
    }

    QK_STEP(0,  kfA, kfB)  QK_STEP(1,  kfB, kfA)
    QK_STEP(2,  kfA, kfB)  QK_STEP(3,  kfB, kfA)
    QK_STEP(4,  kfA, kfB)  QK_STEP(5,  kfB, kfA)
    QK_STEP(6,  kfA, kfB)  QK_STEP(7,  kfB, kfA)
    QK_STEP(8,  kfA, kfB)  QK_STEP(9,  kfB, kfA)
    QK_STEP(10, kfA, kfB)  QK_STEP(11, kfB, kfA)
    QK_STEP(12, kfA, kfB)  QK_STEP(13, kfB, kfA)
    QK_STEP(14, kfA, kfB)  QK_STEP(15, kfB, kfA)
#undef QK_STEP

    // ---- hoisted V chunk-0 prefetch: latency hides under softmax VALU below
    const int c_lim = (jt_any < 0) ? 0 : ((jt_any + 2) >> 1);
    const __bf16* vth = vimg + (size_t)(bh * 8) * 4096 + g * 128 + c16 * 8;
    bf16x8 vbA[8], vbB[8];
    if (0 < c_lim) {
        #pragma unroll
        for (int t = 0; t < 8; ++t) vbA[t] = *(const bf16x8*)(vth + t * 512);
    }

    // ---- softmax over this lane's row: 4 independent per-r partial chains
    float m0 = -INFINITY, m1 = -INFINITY, m2 = -INFINITY, m3 = -INFINITY;
    #pragma unroll
    for (int jt = 0; jt < 16; ++jt) {
        m0 = fmaxf(m0, sacc[jt][0]);
        m1 = fmaxf(m1, sacc[jt][1]);
        m2 = fmaxf(m2, sacc[jt][2]);
        m3 = fmaxf(m3, sacc[jt][3]);
    }
    float m = fmaxf(fmaxf(m0, m1), fmaxf(m2, m3));
    m = fmaxf(m, __shfl_xor(m, 16));
    m = fmaxf(m, __shfl_xor(m, 32));
    float s0 = 0.f, s1 = 0.f, s2 = 0.f, s3 = 0.f;
    #pragma unroll
    for (int jt = 0; jt < 16; ++jt) {
        float e0 = __expf(sacc[jt][0] - m);
        float e1 = __expf(sacc[jt][1] - m);
        float e2 = __expf(sacc[jt][2] - m);
        float e3 = __expf(sacc[jt][3] - m);
        sacc[jt][0] = e0; sacc[jt][1] = e1;
        sacc[jt][2] = e2; sacc[jt][3] = e3;
        s0 += e0; s1 += e1; s2 += e2; s3 += e3;
    }
    float sum = (s0 + s1) + (s2 + s3);
    sum += __shfl_xor(sum, 16);
    sum += __shfl_xor(sum, 32);
    const float inv_l = 1.0f / sum;
    const float u255  = 0.00392156862745098f;  // 1/255 for dead rows

    // ---- normalize, store p (vector, cached), pack bf16x4 -> u64 (sacc dies)
    unsigned long long pnp[16];
    float* prow = p_out + (size_t)(bh * M_ + i) * N_ + g * 4;
    #pragma unroll
    for (int jt = 0; jt < 16; ++jt) {
        f32x4 px;
        #pragma unroll
        for (int r = 0; r < 4; ++r)
            px[r] = dead ? u255 : sacc[jt][r] * inv_l;
        if (jt == 15 && g == 3) {
            f32x2u p2; p2[0] = px[0]; p2[1] = px[1];     // cols 252..254 only
            *(f32x2u*)(prow + 15 * 16) = p2;
            prow[15 * 16 + 2] = px[2];
        } else {
            *(f32x4u*)(prow + jt * 16) = *(f32x4u*)&px;
        }
        union { bf16x4 v; unsigned long long u; } pk;
        #pragma unroll
        for (int r = 0; r < 4; ++r) pk.v[r] = (__bf16)px[r];
        pnp[jt] = pk.u;
    }

    // ---- PV phase: O^T = V^T P^T ; lane (g,c16) holds O[i][vd = vdt*16+g*4+r]
    f32x4 oacc[8];
    #pragma unroll
    for (int t = 0; t < 8; ++t) oacc[t] = (f32x4){0.f, 0.f, 0.f, 0.f};

    const int src0 = ((g & 1) << 5) + c16;   // lane (g_s=(g&1)*2, c16)
    const int src1 = src0 + 16;              // lane (g_s=(g&1)*2+1, c16)
    const bool selhi = (g >= 2);

#define PV_STEP(C, VBc, VBn)                                                   \
    if ((C) < c_lim) {                                                         \
        if ((C) + 1 < c_lim) {                                                 \
            const __bf16* vc = vth + (size_t)((C) + 1) * 4096;                 \
            _Pragma("unroll")                                                  \
            for (int t = 0; t < 8; ++t) VBn[t] = *(const bf16x8*)(vc + t*512); \
        }                                                                      \
        unsigned long long lo0 = __shfl(pnp[2 * (C)],     src0);               \
        unsigned long long lo1 = __shfl(pnp[2 * (C) + 1], src0);               \
        unsigned long long hi0 = __shfl(pnp[2 * (C)],     src1);               \
        unsigned long long hi1 = __shfl(pnp[2 * (C) + 1], src1);               \
        union { struct { unsigned long long x, y; } u; bf16x8 v; } pa8;        \
        pa8.u.x = selhi ? lo1 : lo0;                                           \
        pa8.u.y = selhi ? hi1 : hi0;                                           \
        const bf16x8 pa = pa8.v;                                               \
        __builtin_amdgcn_s_setprio(1);                                         \
        _Pragma("unroll")                                                      \
        for (int vdt = 0; vdt < 8; ++vdt)                                      \
            oacc[vdt] = __builtin_amdgcn_mfma_f32_16x16x32_bf16(VBc[vdt], pa, oacc[vdt], 0, 0, 0); \
        __builtin_amdgcn_s_setprio(0);                                         \
    }

    PV_STEP(0, vbA, vbB)
    PV_STEP(1, vbB, vbA)
    PV_STEP(2, vbA, vbB)
    PV_STEP(3, vbB, vbA)
    PV_STEP(4, vbA, vbB)
    PV_STEP(5, vbB, vbA)
    PV_STEP(6, vbA, vbB)
    PV_STEP(7, vbB, vbA)
#undef PV_STEP

    // ---- write O (plain cached dwordx4; rows < 31 forced to zero)
    float* orow = o_out + ((size_t)(b * M_ + i) * QH_ + h) * VD_ + g * 4;
    #pragma unroll
    for (int vdt = 0; vdt < 8; ++vdt) {
        f32x4 ov;
        #pragma unroll
        for (int r = 0; r < 4; ++r) ov[r] = dead ? 0.f : oacc[vdt][r];
        *(f32x4*)(orow + vdt * 16) = ov;
    }
}

extern "C" void kernel_launch(void* const* d_in, const int* in_sizes, int n_in,
                              void* d_out, int out_size, void* d_ws, size_t ws_size,
                              hipStream_t stream) {
    (void)in_sizes; (void)n_in; (void)ws_size; (void)out_size;
    const float* q = (const float*)d_in[0];
    const float* k = (const float*)d_in[1];
    const float* v = (const float*)d_in[2];
    float* o_out = (float*)d_out;
    float* p_out = o_out + (size_t)B_ * M_ * QH_ * VD_;   // tuple: (o, p) flat

    __bf16* kimg = (__bf16*)d_ws;                          // 32*16*3072*2B = 3.0 MB
    __bf16* vimg = kimg + (size_t)32 * 16 * 3072;          // 32*8*4096*2B  = 2.0 MB

    prep_kv<<<dim3(1280), dim3(256), 0, stream>>>(k, v, kimg, vimg);

    dim3 grid(B_ * QH_ * 256);   // 8192 one-wave blocks; bid&7 = XCD head-group
    dim3 block(64);
    cattn_kernel<<<grid, block, 0, stream>>>(q, kimg, vimg, o_out, p_out);
}